// Round 8
// baseline (172.898 us; speedup 1.0000x reference)
//
#include <hip/hip_runtime.h>
#include <stdint.h>

typedef unsigned short u16;
typedef uint32_t u32;
typedef __bf16 bf16x8 __attribute__((ext_vector_type(8)));
typedef float f32x4 __attribute__((ext_vector_type(4)));
typedef float f32x16 __attribute__((ext_vector_type(16)));
typedef u16 u16x4 __attribute__((ext_vector_type(4)));
typedef u16 u16x8 __attribute__((ext_vector_type(8)));

// ---- problem dims: B=2, S=2048, D=1024, H=16, HD=64, M=4096 ----
// ---- ws layout (u16 element offsets) ----
// x/W tiled (unified): [rowtile=r/64][ktile=k/32][ch=(k%32)/8][row=r%64][8]
//   rt stride = 65536 u16 ; (rt,kt) chunk = 2048 u16 (4KB, LINEAR in ws)
// Q per bh: [qtile=s/128][ch=d/8][row=s%128][8]   (bh stride 131072)
// K per bh: [ktile=s/64][ch=d/8][row=s%64][8]     (A-operand-ready)
// V per bh: [ktile=s/64][kch=(s%64)/8][d][8]      (B-operand-ready V^T)
// proj stages bf16 via global_load_lds: PRE-SWIZZLED global source offset +
// swizzled ds_read frag offsets (involution on byte bits [6:4], both sides).
#define XQ_OFF 0ul
#define XK_OFF 4194304ul
#define XV_OFF 8388608ul
#define WK_OFF 12582912ul
#define WV_OFF 13631488ul
#define Q_OFF  14680064ul
#define K_OFF  18874368ul
#define V_OFF  23068672ul

#define SCQ 0.18033688011112042f  // (1/sqrt(64)) * log2(e), folded into Q

#if __has_builtin(__builtin_amdgcn_exp2f)
#define EXP2F(x) __builtin_amdgcn_exp2f(x)
#else
#define EXP2F(x) exp2f(x)
#endif

__device__ __forceinline__ u16 f2bf(float f) {
  u32 u = __float_as_uint(f);
  u32 r = (u + 0x7fffu + ((u >> 16) & 1u)) >> 16;  // RNE
  return (u16)r;
}

__device__ __forceinline__ u32 pk2(float a, float b) {
  typedef __bf16 bf2_t __attribute__((ext_vector_type(2)));
  typedef float f2_t __attribute__((ext_vector_type(2)));
  f2_t v; v[0] = a; v[1] = b;
  bf2_t h = __builtin_convertvector(v, bf2_t);  // fptrunc = RNE
  union { bf2_t h; u32 u; } cv; cv.h = h; return cv.u;
}

__device__ __forceinline__ void load_lds16(const void* g, void* l) {
  __builtin_amdgcn_global_load_lds(
      (const __attribute__((address_space(1))) u32*)g,
      (__attribute__((address_space(3))) u32*)l, 16, 0, 0);
}

// bank swizzle (byte address involution; touches only bits [6:4])
__device__ __forceinline__ u32 swz(u32 L) {
  return L ^ (((L >> 7) & 1u) << 4) ^ (((L >> 10) & 3u) << 5);
}

// ============================ 1) convert + tile ============================
// (round-0 kernel, verbatim: pure-BW fp32->bf16 retiling pass, ~at BW floor)
__global__ __launch_bounds__(256) void cvt_tile_kernel(
    const float* __restrict__ xq, const float* __restrict__ xk,
    const float* __restrict__ xv, const float* __restrict__ wk,
    const float* __restrict__ wv, u16* __restrict__ ws) {
  __shared__ u16 tile[4096];
  const int bid = blockIdx.x;
  const float* src; size_t dstbase; int rt, ktp;
  if (bid < 3072) {
    int m = bid >> 10, loc = bid & 1023;
    src = (m == 0) ? xq : (m == 1) ? xk : xv;
    dstbase = (size_t)m * 4194304ul;
    rt = loc >> 4; ktp = loc & 15;
  } else {
    int r2 = bid - 3072;
    int m = r2 >> 8, loc = r2 & 255;
    src = m ? wv : wk;
    dstbase = WK_OFF + (size_t)m * 1048576ul;
    rt = loc >> 4; ktp = loc & 15;
  }
  const int t = threadIdx.x;
  const int row0 = t >> 4, c = t & 15;
  const int k = c * 4;
  const float* s = src + (size_t)(rt * 64 + row0) * 1024ul + ktp * 64 + k;
#pragma unroll
  for (int i = 0; i < 4; ++i) {
    float4 v = *(const float4*)(s + (size_t)i * 16384ul);  // row += 16
    int row = row0 + i * 16;
    u32* p = (u32*)(tile + ((k >> 5) * 2048 + ((k >> 3) & 3) * 512 + row * 8 + (k & 7)));
    p[0] = pk2(v.x, v.y);
    p[1] = pk2(v.z, v.w);
  }
  __syncthreads();
  u16* dst = ws + dstbase + (size_t)(rt * 32 + ktp * 2) * 2048ul;
#pragma unroll
  for (int so = 0; so < 4096; so += 2048)
    *(u16x8*)(dst + so + t * 8) = *(const u16x8*)(tile + so + t * 8);
}

// ============================ 2) projection GEMM (bf16, 4-buf 2kt-phase) ===
// (round-7 kernel, verbatim — ~24us, ~1075 TF effective, parked)
__global__ __launch_bounds__(256, 2) void proj_kernel(u16* __restrict__ ws,
                                                      const float* __restrict__ bk,
                                                      const float* __restrict__ bv) {
  const int proj = blockIdx.z;
  const int mtile = blockIdx.x;
  const int ntile = blockIdx.y;
  const u16* A = ws + (size_t)proj * 4194304ul;
  const u16* Bw = ws + ((proj == 0) ? WK_OFF : WV_OFF);
  const float* bias = (proj == 0) ? bk : bv;
  u16* outQ = ws + Q_OFF;
  u16* outK = ws + K_OFF;
  u16* outV = ws + V_OFF;

  const int t = threadIdx.x;
  const int w = t >> 6, lane = t & 63;
  const int wm = w >> 1, wn = w & 1;
  const int g = lane >> 4, c = lane & 15;

  __shared__ __align__(16) u16 smem[32768];

  const u16* Ag = A + (size_t)(2 * mtile) * 65536ul;
  const u16* Bg = Bw + (size_t)(2 * ntile) * 65536ul;
  const u32 t8 = (u32)t * 8u;
  const u32 so = swz((u32)t * 16u) >> 1;  // pre-swizzled source offset (u16)

  u32 poff[4];  // swizzled frag read offsets (u16), shared by A and B sides
#pragma unroll
  for (int mt = 0; mt < 4; ++mt)
    poff[mt] = swz((u32)((g << 10) | ((mt * 16 + c) << 4))) >> 1;

#define PSTAGE(buf, kt)                                            \
  do {                                                             \
    u16* bb = smem + (buf) * 8192;                                 \
    const size_t ko = (size_t)(kt) * 2048ul + so;                  \
    load_lds16(Ag + ko, bb + t8);                                  \
    load_lds16(Ag + 65536ul + ko, bb + 2048 + t8);                 \
    load_lds16(Bg + ko, bb + 4096 + t8);                           \
    load_lds16(Bg + 65536ul + ko, bb + 6144 + t8);                 \
  } while (0)

#define PFRAGS_MFMA(buf)                                                        \
  do {                                                                          \
    const u16* Ap = smem + (buf) * 8192 + wm * 2048;                            \
    const u16* Bp = smem + (buf) * 8192 + 4096 + wn * 2048;                     \
    bf16x8 af[4], bfv[4];                                                       \
    _Pragma("unroll") for (int mt = 0; mt < 4; ++mt)                            \
        af[mt] = *(const bf16x8*)(Ap + poff[mt]);                               \
    _Pragma("unroll") for (int nt = 0; nt < 4; ++nt)                            \
        bfv[nt] = *(const bf16x8*)(Bp + poff[nt]);                              \
    _Pragma("unroll") for (int mt = 0; mt < 4; ++mt)                            \
        _Pragma("unroll") for (int nt = 0; nt < 4; ++nt)                        \
            acc[mt][nt] = __builtin_amdgcn_mfma_f32_16x16x32_bf16(              \
                af[mt], bfv[nt], acc[mt][nt], 0, 0, 0);                         \
  } while (0)

  f32x4 acc[4][4];
#pragma unroll
  for (int mt = 0; mt < 4; ++mt)
#pragma unroll
    for (int nt = 0; nt < 4; ++nt) acc[mt][nt] = (f32x4){0.f, 0.f, 0.f, 0.f};

  PSTAGE(0, 0);
  PSTAGE(1, 1);
  PSTAGE(2, 2);
  PSTAGE(3, 3);

#pragma unroll 1
  for (int p = 0; p < 15; ++p) {
    asm volatile("s_waitcnt vmcnt(8)\n\ts_barrier" ::: "memory");
    const int b0 = (2 * p) & 3;  // p even: bufs 0,1 ; p odd: bufs 2,3
    PFRAGS_MFMA(b0);
    PFRAGS_MFMA(b0 + 1);
    __builtin_amdgcn_s_barrier();  // all readers done -> bufs reusable
    if (p < 14) {
      PSTAGE(b0, 2 * p + 4);
      PSTAGE(b0 + 1, 2 * p + 5);
    }
  }
  asm volatile("s_waitcnt vmcnt(0)\n\ts_barrier" ::: "memory");
  PFRAGS_MFMA(2);
  PFRAGS_MFMA(3);
#undef PSTAGE
#undef PFRAGS_MFMA

  const int m0 = mtile * 128 + wm * 64;
  const int n0 = ntile * 128 + wn * 64;
  if (proj == 2) {
#pragma unroll
    for (int nt = 0; nt < 4; ++nt) {
      const int col = n0 + nt * 16 + c;
      const float bvv = bias[col];
      const int h = col >> 6, d = col & 63;
#pragma unroll
      for (int mt = 0; mt < 4; ++mt) {
        const int mbase = m0 + mt * 16 + g * 4;
        const int b = mbase >> 11;
        const int bh = b * 16 + h;
        const int s = mbase & 2047;
        u16x4 pk;
#pragma unroll
        for (int r = 0; r < 4; ++r) pk[r] = f2bf(acc[mt][nt][r] + bvv);
        size_t idx = (size_t)bh * 131072ul + (size_t)(s >> 6) * 4096ul +
                     (size_t)((s & 63) >> 3) * 512ul + (size_t)d * 8ul + (size_t)(s & 7);
        *(u16x4*)(outV + idx) = pk;
      }
    }
  } else {
    __syncthreads();
    u16* Ew = smem + w * 4096;  // per-wave [ch=d/8][srow 0..64][d&7]
#pragma unroll
    for (int nt = 0; nt < 4; ++nt) {
      const int d = nt * 16 + c;
      const float bvv = bias[n0 + nt * 16 + c];
#pragma unroll
      for (int mt = 0; mt < 4; ++mt) {
#pragma unroll
        for (int r = 0; r < 4; ++r) {
          const int srow = mt * 16 + g * 4 + r;
          float y = acc[mt][nt][r] + bvv;
          if (proj == 0) y *= SCQ;
          Ew[(d >> 3) * 512 + srow * 8 + (d & 7)] = f2bf(y);
        }
      }
    }
    __syncthreads();
    const int b = mtile >> 4;
    const int bh = b * 16 + ntile * 2 + wn;
    if (proj == 0) {
      u16* base = outQ + (size_t)bh * 131072ul + (size_t)(mtile & 15) * 8192ul + wm * 512;
#pragma unroll
      for (int i = 0; i < 8; ++i)
        *(u16x8*)(base + i * 1024 + lane * 8) = *(const u16x8*)(Ew + i * 512 + lane * 8);
    } else {
      u16* base = outK + (size_t)bh * 131072ul + (size_t)((mtile & 15) * 2 + wm) * 4096ul;
#pragma unroll
      for (int i = 0; i < 8; ++i)
        *(u16x8*)(base + i * 512 + lane * 8) = *(const u16x8*)(Ew + i * 512 + lane * 8);
    }
  }
}

// ============================ 3) flash attention (pipelined QK(j+1) ∥ SM(j))
// Round-8: in-wave 1-deep software pipeline. Hold S(j) in regs; per step:
// {vmcnt(4); s_barrier (publishes buf j+1); STAGE(j+3); QK(j+1)->Snext
// [independent MFMA cluster]; exp/pack(j) [VALU overlaps matrix pipe];
// PV(j)}. Kills the per-step QK->exp serial wait (measured: MfmaUtil 26.4%
// == exact matrix-occupancy/wall ratio). 4 LDS bufs (64KB, 2 blocks/CU),
// 3-deep stage issue, vmcnt never 0 until peeled j=30. Named SA/SB sets,
// 2-unrolled loop (rule #20).
__global__ __launch_bounds__(256, 2) void attn_kernel(const u16* __restrict__ ws,
                                                      float* __restrict__ out) {
  const int bh = blockIdx.x, qtile = blockIdx.y;
  const int b = bh >> 4, h = bh & 15;
  const int t = threadIdx.x, w = t >> 6, lane = t & 63;
  const int c32 = lane & 31, g2 = lane >> 5;

  __shared__ __align__(16) u16 Ks[4][4096];
  __shared__ __align__(16) u16 Vs[4][4096];

  const u16* Qg = ws + Q_OFF + (size_t)bh * 131072ul + (size_t)qtile * 8192ul;
  const u16* Kg = ws + K_OFF + (size_t)bh * 131072ul;
  const u16* Vg = ws + V_OFF + (size_t)bh * 131072ul;

  // Q frags (B-operand 32x32x16): col=q=c32, k = ks*16 + g2*8 + e
  bf16x8 qf[4];
#pragma unroll
  for (int ks = 0; ks < 4; ++ks)
    qf[ks] = *(const bf16x8*)(Qg + (size_t)(ks * 2 + g2) * 1024ul +
                              (size_t)(w * 32 + c32) * 8ul);

  f32x16 O0, O1, Lacc, SA0, SA1, SB0, SB1;
#pragma unroll
  for (int i = 0; i < 16; ++i) { O0[i] = 0.f; O1[i] = 0.f; Lacc[i] = 0.f; }

#define STAGE_KV(buf, jj)                                        \
  do {                                                           \
    const u16* Kj = Kg + (size_t)(jj) * 4096ul;                  \
    const u16* Vj = Vg + (size_t)(jj) * 4096ul;                  \
    load_lds16(Kj + (size_t)t * 8ul, &Ks[buf][t * 8]);           \
    load_lds16(Kj + 2048ul + (size_t)t * 8ul, &Ks[buf][2048 + t * 8]); \
    load_lds16(Vj + (size_t)t * 8ul, &Vs[buf][t * 8]);           \
    load_lds16(Vj + 2048ul + (size_t)t * 8ul, &Vs[buf][2048 + t * 8]); \
  } while (0)

// QK for one 64-key chunk: S^T = K * Q^T (rows=keys in regs, cols=q=lanes)
#define QK_CHUNK(Kb, S0v, S1v)                                               \
  do {                                                                       \
    _Pragma("unroll") for (int i = 0; i < 16; ++i) { S0v[i] = 0.f; S1v[i] = 0.f; } \
    __builtin_amdgcn_s_setprio(1);                                           \
    _Pragma("unroll") for (int ks = 0; ks < 4; ++ks) {                       \
      bf16x8 kf0 = *(const bf16x8*)((Kb) + (ks * 2 + g2) * 512 + c32 * 8);   \
      bf16x8 kf1 = *(const bf16x8*)((Kb) + (ks * 2 + g2) * 512 + (32 + c32) * 8); \
      S0v = __builtin_amdgcn_mfma_f32_32x32x16_bf16(kf0, qf[ks], S0v, 0, 0, 0); \
      S1v = __builtin_amdgcn_mfma_f32_32x32x16_bf16(kf1, qf[ks], S1v, 0, 0, 0); \
    }                                                                        \
    __builtin_amdgcn_s_setprio(0);                                           \
  } while (0)

// softmax (exp2, L accumulate), in-reg P pack (cvt_pk + permlane32_swap),
// PV MFMA from Vb
#define SOFTPV(S0v, S1v, Vb)                                                 \
  do {                                                                       \
    _Pragma("unroll") for (int i = 0; i < 16; ++i) {                         \
      S0v[i] = EXP2F(S0v[i]); S1v[i] = EXP2F(S1v[i]);                        \
    }                                                                        \
    Lacc += S0v;                                                             \
    Lacc += S1v;                                                             \
    u32 pa[4][4];                                                            \
    _Pragma("unroll") for (int half = 0; half < 2; ++half) {                 \
      const f32x16& Sx = half ? S1v : S0v;                                   \
      _Pragma("unroll") for (int sub = 0; sub < 2; ++sub) {                  \
        const int rb = sub * 8;                                              \
        u32 q0 = pk2(Sx[rb + 0], Sx[rb + 1]);                                \
        u32 q1 = pk2(Sx[rb + 2], Sx[rb + 3]);                                \
        u32 q2 = pk2(Sx[rb + 4], Sx[rb + 5]);                                \
        u32 q3 = pk2(Sx[rb + 6], Sx[rb + 7]);                                \
        asm volatile("v_permlane32_swap_b32 %0, %1" : "+v"(q0), "+v"(q2));   \
        asm volatile("v_permlane32_swap_b32 %0, %1" : "+v"(q1), "+v"(q3));   \
        const int kstep = half * 2 + sub;                                    \
        pa[kstep][0] = q0; pa[kstep][1] = q1;                                \
        pa[kstep][2] = q2; pa[kstep][3] = q3;                                \
      }                                                                      \
    }                                                                        \
    __builtin_amdgcn_s_setprio(1);                                           \
    _Pragma("unroll") for (int kstep = 0; kstep < 4; ++kstep) {              \
      union { u32 u[4]; bf16x8 b; } pcv;                                     \
      _Pragma("unroll") for (int i = 0; i < 4; ++i) pcv.u[i] = pa[kstep][i]; \
      bf16x8 vf0 = *(const bf16x8*)((Vb) + (kstep * 2 + g2) * 512 + c32 * 8); \
      bf16x8 vf1 = *(const bf16x8*)((Vb) + (kstep * 2 + g2) * 512 + (32 + c32) * 8); \
      O0 = __builtin_amdgcn_mfma_f32_32x32x16_bf16(pcv.b, vf0, O0, 0, 0, 0); \
      O1 = __builtin_amdgcn_mfma_f32_32x32x16_bf16(pcv.b, vf1, O1, 0, 0, 0); \
    }                                                                        \
    __builtin_amdgcn_s_setprio(0);                                           \
  } while (0)

  // prologue: 3-deep stage; publish buf0; QK(0)->SA
  STAGE_KV(0, 0);
  STAGE_KV(1, 1);
  STAGE_KV(2, 2);
  asm volatile("s_waitcnt vmcnt(8)\n\ts_barrier" ::: "memory");
  QK_CHUNK(Ks[0], SA0, SA1);

#pragma unroll 1
  for (int jj = 0; jj < 15; ++jj) {
    const int j = 2 * jj;
    // step j: publish buf[j+1]; QK(j+1)->SB overlaps softmax/PV(j) on SA
    asm volatile("s_waitcnt vmcnt(4)\n\ts_barrier" ::: "memory");
    if (j + 3 < 32) STAGE_KV((j + 3) & 3, j + 3);
    QK_CHUNK(Ks[(j + 1) & 3], SB0, SB1);
    SOFTPV(SA0, SA1, Vs[j & 3]);
    // step j+1: roles swapped (SB live, SA rebuilt)
    asm volatile("s_waitcnt vmcnt(4)\n\ts_barrier" ::: "memory");
    if (j + 4 < 32) STAGE_KV((j + 4) & 3, j + 4);
    QK_CHUNK(Ks[(j + 2) & 3], SA0, SA1);
    SOFTPV(SB0, SB1, Vs[(j + 1) & 3]);
  }
  // tail: j=30 (drain stage31 -> vmcnt(0)), then j=31 (no QK ahead)
  asm volatile("s_waitcnt vmcnt(0)\n\ts_barrier" ::: "memory");
  QK_CHUNK(Ks[3], SB0, SB1);   // chunk 31 (31&3 = 3)
  SOFTPV(SA0, SA1, Vs[2]);     // chunk 30 (30&3 = 2)
  SOFTPV(SB0, SB1, Vs[3]);     // chunk 31
#undef STAGE_KV
#undef QK_CHUNK
#undef SOFTPV

  // ---- L total per q (q = c32 on every lane) ----
  float lp = 0.f;
#pragma unroll
  for (int i = 0; i < 16; ++i) lp += Lacc[i];
  float lA = lp, lB = lp;
  asm volatile("v_permlane32_swap_b32 %0, %1" : "+v"(lA), "+v"(lB));
  const float Ltot = lA + lB;

  // ---- normalize + write fp32 out[b, q, h*64 + d] ----
  const int q0 = qtile * 128 + w * 32;
  float* outb = out + (size_t)(b * 2048 + q0) * 1024ul + h * 64 + c32;
#pragma unroll
  for (int r = 0; r < 16; ++r) {
    const int qr = (r & 3) + 8 * (r >> 2) + 4 * g2;
    int lv = __builtin_amdgcn_ds_bpermute(qr << 2, __float_as_int(Ltot));
    const float inv = 1.0f / __int_as_float(lv);
    float* rp = outb + (size_t)qr * 1024ul;
    rp[0] = O0[r] * inv;
    rp[32] = O1[r] * inv;
  }
}

// ============================ launch ======================================
extern "C" void kernel_launch(void* const* d_in, const int* in_sizes, int n_in,
                              void* d_out, int out_size, void* d_ws, size_t ws_size,
                              hipStream_t stream) {
  const float* q = (const float*)d_in[0];
  const float* k = (const float*)d_in[1];
  const float* v = (const float*)d_in[2];
  const float* wk = (const float*)d_in[3];
  const float* bk = (const float*)d_in[4];
  const float* wv = (const float*)d_in[5];
  const float* bv = (const float*)d_in[6];
  u16* ws = (u16*)d_ws;
  float* out = (float*)d_out;

  cvt_tile_kernel<<<3584, 256, 0, stream>>>(q, k, v, wk, wv, ws);
  proj_kernel<<<dim3(32, 8, 3), 256, 0, stream>>>(ws, bk, bv);
  attn_kernel<<<dim3(32, 16), 256, 0, stream>>>(ws, out);
}